// Round 3
// baseline (130.862 us; speedup 1.0000x reference)
//
#include <hip/hip_runtime.h>
#include <hip/hip_bf16.h>

typedef __attribute__((ext_vector_type(8))) short bf16x8;
typedef __attribute__((ext_vector_type(4))) float f32x4;

// Kinematic tree ancestor tables (full ancestor paths, from reference)
static constexpr int ALEN[24] = {0,1,1,1,2,2,2,3,3,3,4,4,4,4,4,5,5,5,6,6,7,7,8,8};
static constexpr int AOFF[24] = {0,0,1,2,3,5,7,9,12,15,18,22,26,30,34,38,43,48,53,59,65,72,79,87};
static constexpr int AFLAT[95] = {
  0, 0, 0,
  0,1, 0,2, 0,3,
  0,1,4, 0,2,5, 0,3,6,
  0,1,4,7, 0,2,5,8, 0,3,6,9, 0,3,6,9, 0,3,6,9,
  0,3,6,9,12, 0,3,6,9,13, 0,3,6,9,14,
  0,3,6,9,13,16, 0,3,6,9,14,17,
  0,3,6,9,13,16,18, 0,3,6,9,14,17,19,
  0,3,6,9,13,16,18,20, 0,3,6,9,14,17,19,21};

static __device__ __forceinline__ unsigned short f2bf(float f) {
  unsigned int u = __float_as_uint(f);
  u = (u + 0x7fffu + ((u >> 16) & 1u)) >> 16;   // RTNE
  return (unsigned short)u;
}

// ---------------------------------------------------------------------------
// K1: fused combine with 2-level K-split (z-chunks of 128 h, 4 waves x 32 h).
//   G[147][401] = [ktd_head(144x1024); deccam_w[:, :1024](3x1024)] @ [fc2_w | fc2_b]
//   H[13][267]  = [decshape_w(10x1024); deccam_w[:,1024:2048](3x1024)] @ [fc1_w | fc1_b]
// blockIdx.y < 37 -> G o-tiles; y in [37,41) -> H o-tiles. blockIdx.z = h-chunk.
// Partials Gp[8][147*401] / Hp[8][13*267] summed in assembleM.
// ---------------------------------------------------------------------------
__global__ __launch_bounds__(256) void combine_part(const float* __restrict__ ktd,
                                                    const float* __restrict__ dcw,
                                                    const float* __restrict__ dsw,
                                                    const float* __restrict__ w2,
                                                    const float* __restrict__ b2,
                                                    const float* __restrict__ w1,
                                                    const float* __restrict__ b1,
                                                    float* __restrict__ Gp,
                                                    float* __restrict__ Hp) {
  const bool isH = blockIdx.y >= 37;
  if (isH && blockIdx.x >= 5) return;              // H: c < 320 only (uniform exit)
  const int w = threadIdx.x >> 6, lane = threadIdx.x & 63;
  const int c = blockIdx.x * 64 + lane;
  const int h0 = blockIdx.z * 128 + w * 32;
  __shared__ float red[4][4][64];

  const float* vp[4];
  int o0;
  if (!isH) {
    o0 = blockIdx.y * 4;
    #pragma unroll
    for (int oi = 0; oi < 4; oi++) {
      int o = o0 + oi; if (o > 146) o = 146;
      vp[oi] = (o < 144) ? (ktd + (size_t)o * 1078) : (dcw + (size_t)(o - 144) * 2051);
    }
  } else {
    o0 = (blockIdx.y - 37) * 4;
    #pragma unroll
    for (int oi = 0; oi < 4; oi++) {
      int o = o0 + oi; if (o > 12) o = 12;
      vp[oi] = (o < 10) ? (dsw + (size_t)o * 1024) : (dcw + (size_t)(o - 10) * 2051 + 1024);
    }
  }

  float acc[4] = {0.f, 0.f, 0.f, 0.f};
  if (!isH) {
    #pragma unroll 16
    for (int hh = 0; hh < 32; hh++) {
      int h = h0 + hh;
      float wv = (c < 400) ? w2[h * 400 + c] : ((c == 400) ? b2[h] : 0.f);
      #pragma unroll
      for (int oi = 0; oi < 4; oi++) acc[oi] += vp[oi][h] * wv;
    }
  } else {
    #pragma unroll 16
    for (int hh = 0; hh < 32; hh++) {
      int h = h0 + hh;
      float wv = (c < 266) ? w1[h * 266 + c] : ((c == 266) ? b1[h] : 0.f);
      #pragma unroll
      for (int oi = 0; oi < 4; oi++) acc[oi] += vp[oi][h] * wv;
    }
  }

  #pragma unroll
  for (int oi = 0; oi < 4; oi++) red[w][oi][lane] = acc[oi];
  __syncthreads();
  if (w == 0) {
    #pragma unroll
    for (int oi = 0; oi < 4; oi++) {
      int o = o0 + oi;
      float s = red[0][oi][lane] + red[1][oi][lane] + red[2][oi][lane] + red[3][oi][lane];
      if (!isH) {
        if (o < 147 && c <= 400) Gp[(size_t)blockIdx.z * 59200 + o * 401 + c] = s;
      } else {
        if (o < 13 && c <= 266) Hp[(size_t)blockIdx.z * 3520 + o * 267 + c] = s;
      }
    }
  }
}

static __device__ __forceinline__ float gsum(const float* __restrict__ Gp, int t, int c) {
  float s = 0.f;
  #pragma unroll
  for (int z = 0; z < 8; z++) s += Gp[(size_t)z * 59200 + t * 401 + c];
  return s;
}
static __device__ __forceinline__ float hsum(const float* __restrict__ Hp, int t, int c) {
  float s = 0.f;
  #pragma unroll
  for (int z = 0; z < 8; z++) s += Hp[(size_t)z * 3520 + t * 267 + c];
  return s;
}

// ---------------------------------------------------------------------------
// K2: assemble fp32 M0[160][424] + bias C0[160], summing 8 K-chunk partials.
// z layout: [0:256)=x  [256:400)=init_pose  [400:410)=init_shape  [410:413)=init_cam
// out rows: [0:3)=cam  [3:147)=pose BASE (no ancestors, no +init_pose)  [147:157)=shape
// ---------------------------------------------------------------------------
__global__ __launch_bounds__(256) void assembleM(const float* __restrict__ Gp,
                                                 const float* __restrict__ Hp,
                                                 const float* __restrict__ dcw,
                                                 const float* __restrict__ dcb,
                                                 const float* __restrict__ dsb,
                                                 const float* __restrict__ ktd,
                                                 const float* __restrict__ ktdb,
                                                 float* __restrict__ M0,
                                                 float* __restrict__ C0) {
  int o = blockIdx.x;
  for (int c = threadIdx.x; c < 424; c += 256) {
    float val = 0.f;
    if (c < 413) {
      if (o < 3) {
        if (c < 400) val += gsum(Gp, 144 + o, c);
        if (c < 256) val += hsum(Hp, 10 + o, c);
        if (c >= 400 && c < 410) val += hsum(Hp, 10 + o, 256 + (c - 400));
        if (c >= 410) {
          val += dcw[(size_t)o * 2051 + 2048 + (c - 410)];
          if ((c - 410) == o) val += 1.f;
        }
      } else if (o < 147) {
        int t = o - 3, j = t / 6;
        if (c < 400) val = gsum(Gp, t, c);
        int cj = c - 256 - j;            // init_pose[..., j:j+6] quirk slice
        if (cj >= 0 && cj < 6) val += ktd[(size_t)t * 1078 + 1024 + 6 * ALEN[j] + cj];
      } else if (o < 157) {
        int s = o - 147;
        if (c < 256) val = hsum(Hp, s, c);
        if (c >= 400 && c < 410) {
          val += hsum(Hp, s, 256 + (c - 400));
          if ((c - 400) == s) val += 1.f;
        }
      }
    }
    M0[o * 424 + c] = val;
  }
  if (threadIdx.x == 0 && o < 157) {
    float bv;
    if (o < 3)        bv = gsum(Gp, 144 + o, 400) + hsum(Hp, 10 + o, 266) + dcb[o];
    else if (o < 147) bv = gsum(Gp, o - 3, 400) + ktdb[o - 3];
    else              bv = hsum(Hp, o - 147, 266) + dsb[o - 147];
    C0[o] = bv;
  }
}

// ---------------------------------------------------------------------------
// K3: S[144][144]: pose = S @ base (forward substitution over the kinematic
// tree). One thread per COLUMN c; s[] stays in VGPRs (all indices static).
// ---------------------------------------------------------------------------
__global__ __launch_bounds__(192) void computeS(const float* __restrict__ kw,
                                                float* __restrict__ S) {
  int c = threadIdx.x;
  if (c >= 144) return;
  float s[144];
  #pragma unroll
  for (int j = 0; j < 24; j++) {
    float v[6];
    #pragma unroll
    for (int r = 0; r < 6; r++) v[r] = (6 * j + r == c) ? 1.f : 0.f;
    #pragma unroll
    for (int a = 0; a < 8; a++) {
      if (a < ALEN[j]) {
        int anc = AFLAT[AOFF[j] + a];
        #pragma unroll
        for (int r = 0; r < 6; r++) {
          const float* w = kw + (size_t)(6 * j + r) * 1078 + 1024 + 6 * a;
          v[r] += w[0] * s[anc * 6 + 0] + w[1] * s[anc * 6 + 1] + w[2] * s[anc * 6 + 2]
                + w[3] * s[anc * 6 + 3] + w[4] * s[anc * 6 + 4] + w[5] * s[anc * 6 + 5];
        }
      }
    }
    #pragma unroll
    for (int r = 0; r < 6; r++) s[6 * j + r] = v[r];
  }
  #pragma unroll
  for (int t = 0; t < 144; t++) S[t * 144 + c] = s[t];
}

// ---------------------------------------------------------------------------
// K4: fold S into M: Mb[3+t][c] = bf16( sum_k S[t][k]*M0[3+k][c] + (c==256+t) )
//     cam/shape rows pass through. Cb likewise.
// ---------------------------------------------------------------------------
__global__ __launch_bounds__(256) void foldS(const float* __restrict__ S,
                                             const float* __restrict__ M0,
                                             const float* __restrict__ C0,
                                             unsigned short* __restrict__ Mb,
                                             float* __restrict__ Cb) {
  int o = blockIdx.x;
  if (o < 3 || o >= 147) {
    for (int c = threadIdx.x; c < 424; c += 256)
      Mb[o * 424 + c] = f2bf(M0[o * 424 + c]);
    if (threadIdx.x == 0) Cb[o] = (o < 157) ? C0[o] : 0.f;
    return;
  }
  int t = o - 3;
  __shared__ float Sl[144];
  if (threadIdx.x < 144) Sl[threadIdx.x] = S[t * 144 + threadIdx.x];
  __syncthreads();
  for (int c = threadIdx.x; c < 424; c += 256) {
    float acc = 0.f;
    #pragma unroll 8
    for (int k = 0; k < 144; k++) acc += Sl[k] * M0[(3 + k) * 424 + c];
    if (c == 256 + t) acc += 1.f;          // + init_pose fold
    Mb[o * 424 + c] = f2bf(acc);
  }
  if (threadIdx.x == 0) {
    float acc = 0.f;
    for (int k = 0; k < 144; k++) acc += Sl[k] * C0[3 + k];
    Cb[o] = acc;
  }
}

// ---------------------------------------------------------------------------
// K5: main GEMM  out[rows x 157] = Z[rows x 424] @ Mb^T + Cb  (MFMA 16x16x32)
//   64 rows/block, 4 waves, wave w handles rows [16w,16w+16); full N=160/wave
// ---------------------------------------------------------------------------
__global__ __launch_bounds__(256) void main_gemm(const float* __restrict__ x,
                                                 const float* __restrict__ ipose,
                                                 const float* __restrict__ ishape,
                                                 const float* __restrict__ icam,
                                                 const unsigned short* __restrict__ Mb,
                                                 const float* __restrict__ Cb,
                                                 float* __restrict__ out,
                                                 int rows) {
  __shared__ unsigned short zt[64 * 424];      // 54.3 KB, bf16 Z tile
  const int rowbase = blockIdx.x * 64;
  const int tid = threadIdx.x;

  // stage x (64 rows x 256)
  const float4* x4 = (const float4*)(x + (size_t)rowbase * 256);
  for (int i = tid; i < 64 * 64; i += 256) {
    int r = i >> 6, c4 = i & 63;
    float4 v = x4[r * 64 + c4];
    ushort4 b; b.x = f2bf(v.x); b.y = f2bf(v.y); b.z = f2bf(v.z); b.w = f2bf(v.w);
    *(ushort4*)&zt[r * 424 + c4 * 4] = b;
  }
  // stage init_pose (64 rows x 144) at col 256
  const float4* p4 = (const float4*)(ipose + (size_t)rowbase * 144);
  for (int i = tid; i < 64 * 36; i += 256) {
    int r = i / 36, c4 = i % 36;
    float4 v = p4[r * 36 + c4];
    ushort4 b; b.x = f2bf(v.x); b.y = f2bf(v.y); b.z = f2bf(v.z); b.w = f2bf(v.w);
    *(ushort4*)&zt[r * 424 + 256 + c4 * 4] = b;
  }
  // init_shape (10) at col 400, init_cam (3) at col 410, zeros 413..423
  for (int i = tid; i < 64 * 10; i += 256) {
    int r = i / 10, cc = i % 10;
    zt[r * 424 + 400 + cc] = f2bf(ishape[(size_t)(rowbase + r) * 10 + cc]);
  }
  for (int i = tid; i < 64 * 3; i += 256) {
    int r = i / 3, cc = i % 3;
    zt[r * 424 + 410 + cc] = f2bf(icam[(size_t)(rowbase + r) * 3 + cc]);
  }
  for (int i = tid; i < 64 * 11; i += 256) {
    int r = i / 11, cc = i % 11;
    zt[r * 424 + 413 + cc] = 0;
  }
  __syncthreads();

  const int wv = tid >> 6, lane = tid & 63;
  const int m = lane & 15, g = lane >> 4;
  const int r0 = wv * 16;

  f32x4 acc[10];
  #pragma unroll
  for (int n = 0; n < 10; n++) acc[n] = (f32x4){0.f, 0.f, 0.f, 0.f};

  for (int k = 0; k < 13; k++) {
    bf16x8 a = *(const bf16x8*)&zt[(r0 + m) * 424 + k * 32 + g * 8];
    #pragma unroll
    for (int n = 0; n < 10; n++) {
      bf16x8 b = *(const bf16x8*)&Mb[(size_t)(n * 16 + m) * 424 + k * 32 + g * 8];
      acc[n] = __builtin_amdgcn_mfma_f32_16x16x32_bf16(a, b, acc[n], 0, 0, 0);
    }
  }

  // epilogue: C/D layout col=lane&15, row=(lane>>4)*4+reg  [m89-verified]
  #pragma unroll
  for (int n = 0; n < 10; n++) {
    int col = n * 16 + m;
    if (col >= 157) continue;
    float bias = Cb[col];
    #pragma unroll
    for (int q = 0; q < 4; q++) {
      int row = rowbase + r0 + g * 4 + q;
      out[(size_t)row * 157 + col] = acc[n][q] + bias;
    }
  }
}

// ---------------------------------------------------------------------------
extern "C" void kernel_launch(void* const* d_in, const int* in_sizes, int n_in,
                              void* d_out, int out_size, void* d_ws, size_t ws_size,
                              hipStream_t stream) {
  const float* x      = (const float*)d_in[0];
  const float* ipose  = (const float*)d_in[1];
  const float* ishape = (const float*)d_in[2];
  const float* icam   = (const float*)d_in[3];
  const float* fc1w   = (const float*)d_in[4];
  const float* fc1b   = (const float*)d_in[5];
  const float* fc2w   = (const float*)d_in[6];
  const float* fc2b   = (const float*)d_in[7];
  const float* dsw    = (const float*)d_in[8];
  const float* dsb    = (const float*)d_in[9];
  const float* dcw    = (const float*)d_in[10];
  const float* dcb    = (const float*)d_in[11];
  const float* ktd    = (const float*)d_in[12];
  const float* ktdb   = (const float*)d_in[13];
  int rows = in_sizes[0] / 256;
  float* ws = (float*)d_ws;

  float* Gp = ws;                                      // 8*59200 = 473600 f
  float* Hp = ws + 473600;                             // 8*3520  = 28160 f -> 501760
  float* M0 = ws + 501760;                             // 160*424 = 67840 f -> 569600
  float* C0 = ws + 569600;                             // 160 f -> 569760
  float* S  = ws + 569760;                             // 144*144 = 20736 f -> 590496
  float* Cb = ws + 590496;                             // 160 f -> 590656
  unsigned short* Mb = (unsigned short*)(ws + 590656); // byte 2362624 (16-aligned)

  combine_part<<<dim3(7, 41, 8), 256, 0, stream>>>(ktd, dcw, dsw, fc2w, fc2b,
                                                   fc1w, fc1b, Gp, Hp);
  assembleM<<<160, 256, 0, stream>>>(Gp, Hp, dcw, dcb, dsb, ktd, ktdb, M0, C0);
  computeS<<<1, 192, 0, stream>>>(ktd, S);
  foldS<<<160, 256, 0, stream>>>(S, M0, C0, Mb, Cb);
  main_gemm<<<rows / 64, 256, 0, stream>>>(x, ipose, ishape, icam, Mb, Cb,
                                           (float*)d_out, rows);
}

// Round 4
// 101.823 us; speedup vs baseline: 1.2852x; 1.2852x over previous
//
#include <hip/hip_runtime.h>
#include <hip/hip_bf16.h>

typedef __attribute__((ext_vector_type(8))) short bf16x8;
typedef __attribute__((ext_vector_type(4))) float f32x4;

// Kinematic tree ancestor tables (full ancestor paths, from reference)
static constexpr int ALEN[24] = {0,1,1,1,2,2,2,3,3,3,4,4,4,4,4,5,5,5,6,6,7,7,8,8};
static constexpr int AOFF[24] = {0,0,1,2,3,5,7,9,12,15,18,22,26,30,34,38,43,48,53,59,65,72,79,87};
static constexpr int AFLAT[95] = {
  0, 0, 0,
  0,1, 0,2, 0,3,
  0,1,4, 0,2,5, 0,3,6,
  0,1,4,7, 0,2,5,8, 0,3,6,9, 0,3,6,9, 0,3,6,9,
  0,3,6,9,12, 0,3,6,9,13, 0,3,6,9,14,
  0,3,6,9,13,16, 0,3,6,9,14,17,
  0,3,6,9,13,16,18, 0,3,6,9,14,17,19,
  0,3,6,9,13,16,18,20, 0,3,6,9,14,17,19,21};

static __device__ __forceinline__ unsigned short f2bf(float f) {
  unsigned int u = __float_as_uint(f);
  u = (u + 0x7fffu + ((u >> 16) & 1u)) >> 16;   // RTNE
  return (unsigned short)u;
}

static __device__ __forceinline__ bf16x8 pack8(float4 lo, float4 hi) {
  bf16x8 r;
  r[0] = (short)f2bf(lo.x); r[1] = (short)f2bf(lo.y);
  r[2] = (short)f2bf(lo.z); r[3] = (short)f2bf(lo.w);
  r[4] = (short)f2bf(hi.x); r[5] = (short)f2bf(hi.y);
  r[6] = (short)f2bf(hi.z); r[7] = (short)f2bf(hi.w);
  return r;
}

// ---------------------------------------------------------------------------
// K1: fused combine with 2-level K-split (z-chunks of 128 h, 4 waves x 32 h).
//   G[147][401] = [ktd_head(144x1024); deccam_w[:, :1024](3x1024)] @ [fc2_w | fc2_b]
//   H[13][267]  = [decshape_w(10x1024); deccam_w[:,1024:2048](3x1024)] @ [fc1_w | fc1_b]
// ---------------------------------------------------------------------------
__global__ __launch_bounds__(256) void combine_part(const float* __restrict__ ktd,
                                                    const float* __restrict__ dcw,
                                                    const float* __restrict__ dsw,
                                                    const float* __restrict__ w2,
                                                    const float* __restrict__ b2,
                                                    const float* __restrict__ w1,
                                                    const float* __restrict__ b1,
                                                    float* __restrict__ Gp,
                                                    float* __restrict__ Hp) {
  const bool isH = blockIdx.y >= 37;
  if (isH && blockIdx.x >= 5) return;              // H: c < 320 only (uniform exit)
  const int w = threadIdx.x >> 6, lane = threadIdx.x & 63;
  const int c = blockIdx.x * 64 + lane;
  const int h0 = blockIdx.z * 128 + w * 32;
  __shared__ float red[4][4][64];

  const float* vp[4];
  int o0;
  if (!isH) {
    o0 = blockIdx.y * 4;
    #pragma unroll
    for (int oi = 0; oi < 4; oi++) {
      int o = o0 + oi; if (o > 146) o = 146;
      vp[oi] = (o < 144) ? (ktd + (size_t)o * 1078) : (dcw + (size_t)(o - 144) * 2051);
    }
  } else {
    o0 = (blockIdx.y - 37) * 4;
    #pragma unroll
    for (int oi = 0; oi < 4; oi++) {
      int o = o0 + oi; if (o > 12) o = 12;
      vp[oi] = (o < 10) ? (dsw + (size_t)o * 1024) : (dcw + (size_t)(o - 10) * 2051 + 1024);
    }
  }

  float acc[4] = {0.f, 0.f, 0.f, 0.f};
  if (!isH) {
    #pragma unroll 16
    for (int hh = 0; hh < 32; hh++) {
      int h = h0 + hh;
      float wv = (c < 400) ? w2[h * 400 + c] : ((c == 400) ? b2[h] : 0.f);
      #pragma unroll
      for (int oi = 0; oi < 4; oi++) acc[oi] += vp[oi][h] * wv;
    }
  } else {
    #pragma unroll 16
    for (int hh = 0; hh < 32; hh++) {
      int h = h0 + hh;
      float wv = (c < 266) ? w1[h * 266 + c] : ((c == 266) ? b1[h] : 0.f);
      #pragma unroll
      for (int oi = 0; oi < 4; oi++) acc[oi] += vp[oi][h] * wv;
    }
  }

  #pragma unroll
  for (int oi = 0; oi < 4; oi++) red[w][oi][lane] = acc[oi];
  __syncthreads();
  if (w == 0) {
    #pragma unroll
    for (int oi = 0; oi < 4; oi++) {
      int o = o0 + oi;
      float s = red[0][oi][lane] + red[1][oi][lane] + red[2][oi][lane] + red[3][oi][lane];
      if (!isH) {
        if (o < 147 && c <= 400) Gp[(size_t)blockIdx.z * 59200 + o * 401 + c] = s;
      } else {
        if (o < 13 && c <= 266) Hp[(size_t)blockIdx.z * 3520 + o * 267 + c] = s;
      }
    }
  }
}

static __device__ __forceinline__ float gsum(const float* __restrict__ Gp, int t, int c) {
  float s = 0.f;
  #pragma unroll
  for (int z = 0; z < 8; z++) s += Gp[(size_t)z * 59200 + t * 401 + c];
  return s;
}
static __device__ __forceinline__ float hsum(const float* __restrict__ Hp, int t, int c) {
  float s = 0.f;
  #pragma unroll
  for (int z = 0; z < 8; z++) s += Hp[(size_t)z * 3520 + t * 267 + c];
  return s;
}

// ---------------------------------------------------------------------------
// K2: assemble fp32 M0[160][424] + bias C0[160], summing 8 K-chunk partials.
// z layout: [0:256)=x  [256:400)=init_pose  [400:410)=init_shape  [410:413)=init_cam
// out rows: [0:3)=cam  [3:147)=pose BASE  [147:157)=shape
// ---------------------------------------------------------------------------
__global__ __launch_bounds__(256) void assembleM(const float* __restrict__ Gp,
                                                 const float* __restrict__ Hp,
                                                 const float* __restrict__ dcw,
                                                 const float* __restrict__ dcb,
                                                 const float* __restrict__ dsb,
                                                 const float* __restrict__ ktd,
                                                 const float* __restrict__ ktdb,
                                                 float* __restrict__ M0,
                                                 float* __restrict__ C0) {
  int o = blockIdx.x;
  for (int c = threadIdx.x; c < 424; c += 256) {
    float val = 0.f;
    if (c < 413) {
      if (o < 3) {
        if (c < 400) val += gsum(Gp, 144 + o, c);
        if (c < 256) val += hsum(Hp, 10 + o, c);
        if (c >= 400 && c < 410) val += hsum(Hp, 10 + o, 256 + (c - 400));
        if (c >= 410) {
          val += dcw[(size_t)o * 2051 + 2048 + (c - 410)];
          if ((c - 410) == o) val += 1.f;
        }
      } else if (o < 147) {
        int t = o - 3, j = t / 6;
        if (c < 400) val = gsum(Gp, t, c);
        int cj = c - 256 - j;            // init_pose[..., j:j+6] quirk slice
        if (cj >= 0 && cj < 6) val += ktd[(size_t)t * 1078 + 1024 + 6 * ALEN[j] + cj];
      } else if (o < 157) {
        int s = o - 147;
        if (c < 256) val = hsum(Hp, s, c);
        if (c >= 400 && c < 410) {
          val += hsum(Hp, s, 256 + (c - 400));
          if ((c - 400) == s) val += 1.f;
        }
      }
    }
    M0[o * 424 + c] = val;
  }
  if (threadIdx.x == 0 && o < 157) {
    float bv;
    if (o < 3)        bv = gsum(Gp, 144 + o, 400) + hsum(Hp, 10 + o, 266) + dcb[o];
    else if (o < 147) bv = gsum(Gp, o - 3, 400) + ktdb[o - 3];
    else              bv = hsum(Hp, o - 147, 266) + dsb[o - 147];
    C0[o] = bv;
  }
}

// ---------------------------------------------------------------------------
// K3: S[144][144]: pose = S @ base (forward substitution). Weights staged in
// LDS once (coalesced) so the recurrence reads LDS broadcasts, not serial
// uniform s_loads. One thread per column c.
// ---------------------------------------------------------------------------
__global__ __launch_bounds__(192) void computeS(const float* __restrict__ kw,
                                                float* __restrict__ S) {
  __shared__ float Wl[144][48];        // kw[t][1024 + 6a + r], a<8 -> 48 cols
  for (int i = threadIdx.x; i < 144 * 24; i += 192) {
    int t = i / 24, ch = i % 24;
    *(float2*)&Wl[t][ch * 2] = *(const float2*)(kw + (size_t)t * 1078 + 1024 + ch * 2);
  }
  __syncthreads();
  int c = threadIdx.x;
  if (c >= 144) return;
  float s[144];
  #pragma unroll
  for (int j = 0; j < 24; j++) {
    float v[6];
    #pragma unroll
    for (int r = 0; r < 6; r++) v[r] = (6 * j + r == c) ? 1.f : 0.f;
    #pragma unroll
    for (int a = 0; a < 8; a++) {
      if (a < ALEN[j]) {
        int anc = AFLAT[AOFF[j] + a];
        #pragma unroll
        for (int r = 0; r < 6; r++) {
          const float* w = &Wl[6 * j + r][6 * a];
          v[r] += w[0] * s[anc * 6 + 0] + w[1] * s[anc * 6 + 1] + w[2] * s[anc * 6 + 2]
                + w[3] * s[anc * 6 + 3] + w[4] * s[anc * 6 + 4] + w[5] * s[anc * 6 + 5];
        }
      }
    }
    #pragma unroll
    for (int r = 0; r < 6; r++) s[6 * j + r] = v[r];
  }
  #pragma unroll
  for (int t = 0; t < 144; t++) S[t * 144 + c] = s[t];
}

// ---------------------------------------------------------------------------
// K4: fold S into M: Mb[3+t][c] = bf16( sum_k S[t][k]*M0[3+k][c] + (c==256+t) )
// ---------------------------------------------------------------------------
__global__ __launch_bounds__(256) void foldS(const float* __restrict__ S,
                                             const float* __restrict__ M0,
                                             const float* __restrict__ C0,
                                             unsigned short* __restrict__ Mb,
                                             float* __restrict__ Cb) {
  int o = blockIdx.x;
  if (o < 3 || o >= 147) {
    for (int c = threadIdx.x; c < 424; c += 256)
      Mb[o * 424 + c] = f2bf(M0[o * 424 + c]);
    if (threadIdx.x == 0) Cb[o] = (o < 157) ? C0[o] : 0.f;
    return;
  }
  int t = o - 3;
  __shared__ float Sl[144];
  if (threadIdx.x < 144) Sl[threadIdx.x] = S[t * 144 + threadIdx.x];
  __syncthreads();
  for (int c = threadIdx.x; c < 424; c += 256) {
    float acc = 0.f;
    #pragma unroll 16
    for (int k = 0; k < 144; k++) acc += Sl[k] * M0[(3 + k) * 424 + c];
    if (c == 256 + t) acc += 1.f;          // + init_pose fold
    Mb[o * 424 + c] = f2bf(acc);
  }
  if (threadIdx.x == 0) {
    float acc = 0.f;
    for (int k = 0; k < 144; k++) acc += Sl[k] * C0[3 + k];
    Cb[o] = acc;
  }
}

// ---------------------------------------------------------------------------
// K5: main GEMM  out[rows x 157] = Z[rows x 424] @ Mb^T + Cb  (MFMA 16x16x32)
// No LDS, no barriers. 128-thread blocks = 2 waves x 16 rows; blockIdx.y
// selects N-half (80 cols, acc[5]). A-fragments loaded per-lane directly from
// the fp32 inputs (128B-contiguous per 4-lane g-group), converted in-reg.
// ---------------------------------------------------------------------------
__global__ __launch_bounds__(128, 4) void main_gemm(const float* __restrict__ x,
                                                    const float* __restrict__ ipose,
                                                    const float* __restrict__ ishape,
                                                    const float* __restrict__ icam,
                                                    const unsigned short* __restrict__ Mb,
                                                    const float* __restrict__ Cb,
                                                    float* __restrict__ out) {
  const int w = threadIdx.x >> 6, lane = threadIdx.x & 63;
  const int m = lane & 15, g = lane >> 4;
  const int rowbase = blockIdx.x * 32 + w * 16;
  const int h = blockIdx.y;                     // N-half: cols [80h, 80h+80)
  const int row = rowbase + m;
  const float* xr = x + (size_t)row * 256;
  const float* pr = ipose + (size_t)row * 144;

  f32x4 acc[5];
  #pragma unroll
  for (int n = 0; n < 5; n++) acc[n] = (f32x4){0.f, 0.f, 0.f, 0.f};

  #pragma unroll
  for (int k = 0; k < 13; k++) {
    bf16x8 a;
    if (k < 8) {
      const float* p = xr + k * 32 + g * 8;
      a = pack8(*(const float4*)p, *(const float4*)(p + 4));
    } else if (k < 12) {
      const float* p = pr + k * 32 + g * 8 - 256;
      a = pack8(*(const float4*)p, *(const float4*)(p + 4));
    } else {
      if (g < 2) {
        const float* p = pr + 128 + g * 8;
        a = pack8(*(const float4*)p, *(const float4*)(p + 4));
      } else if (g == 2) {
        const float* p = ishape + (size_t)row * 10;
        float4 lo = make_float4(p[0], p[1], p[2], p[3]);
        float4 hi = make_float4(p[4], p[5], p[6], p[7]);
        a = pack8(lo, hi);
      } else {
        const float* p = ishape + (size_t)row * 10;
        const float* q = icam + (size_t)row * 3;
        float4 lo = make_float4(p[8], p[9], q[0], q[1]);
        float4 hi = make_float4(q[2], 0.f, 0.f, 0.f);
        a = pack8(lo, hi);
      }
    }
    #pragma unroll
    for (int n = 0; n < 5; n++) {
      bf16x8 b = *(const bf16x8*)&Mb[(size_t)(h * 80 + n * 16 + m) * 424 + k * 32 + g * 8];
      acc[n] = __builtin_amdgcn_mfma_f32_16x16x32_bf16(a, b, acc[n], 0, 0, 0);
    }
  }

  // epilogue: C/D layout col=lane&15, row=(lane>>4)*4+reg  [m89-verified]
  #pragma unroll
  for (int n = 0; n < 5; n++) {
    int col = h * 80 + n * 16 + m;
    if (col < 157) {
      float bias = Cb[col];
      #pragma unroll
      for (int q = 0; q < 4; q++)
        out[(size_t)(rowbase + g * 4 + q) * 157 + col] = acc[n][q] + bias;
    }
  }
}

// ---------------------------------------------------------------------------
extern "C" void kernel_launch(void* const* d_in, const int* in_sizes, int n_in,
                              void* d_out, int out_size, void* d_ws, size_t ws_size,
                              hipStream_t stream) {
  const float* x      = (const float*)d_in[0];
  const float* ipose  = (const float*)d_in[1];
  const float* ishape = (const float*)d_in[2];
  const float* icam   = (const float*)d_in[3];
  const float* fc1w   = (const float*)d_in[4];
  const float* fc1b   = (const float*)d_in[5];
  const float* fc2w   = (const float*)d_in[6];
  const float* fc2b   = (const float*)d_in[7];
  const float* dsw    = (const float*)d_in[8];
  const float* dsb    = (const float*)d_in[9];
  const float* dcw    = (const float*)d_in[10];
  const float* dcb    = (const float*)d_in[11];
  const float* ktd    = (const float*)d_in[12];
  const float* ktdb   = (const float*)d_in[13];
  int rows = in_sizes[0] / 256;
  float* ws = (float*)d_ws;

  float* Gp = ws;                                      // 8*59200 = 473600 f
  float* Hp = ws + 473600;                             // 8*3520  = 28160 f -> 501760
  float* M0 = ws + 501760;                             // 160*424 = 67840 f -> 569600
  float* C0 = ws + 569600;                             // 160 f -> 569760
  float* S  = ws + 569760;                             // 144*144 = 20736 f -> 590496
  float* Cb = ws + 590496;                             // 160 f -> 590656
  unsigned short* Mb = (unsigned short*)(ws + 590656); // byte 2362624 (16-aligned)

  computeS<<<1, 192, 0, stream>>>(ktd, S);
  combine_part<<<dim3(7, 41, 8), 256, 0, stream>>>(ktd, dcw, dsw, fc2w, fc2b,
                                                   fc1w, fc1b, Gp, Hp);
  assembleM<<<160, 256, 0, stream>>>(Gp, Hp, dcw, dcb, dsb, ktd, ktdb, M0, C0);
  foldS<<<160, 256, 0, stream>>>(S, M0, C0, Mb, Cb);
  main_gemm<<<dim3(rows / 32, 2), 128, 0, stream>>>(x, ipose, ishape, icam, Mb, Cb,
                                                    (float*)d_out);
}

// Round 5
// 100.157 us; speedup vs baseline: 1.3066x; 1.0166x over previous
//
#include <hip/hip_runtime.h>
#include <hip/hip_bf16.h>

typedef __attribute__((ext_vector_type(8))) short bf16x8;
typedef __attribute__((ext_vector_type(4))) float f32x4;

// Kinematic tree ancestor tables (full ancestor paths, from reference)
static constexpr int ALEN[24] = {0,1,1,1,2,2,2,3,3,3,4,4,4,4,4,5,5,5,6,6,7,7,8,8};
static constexpr int AOFF[24] = {0,0,1,2,3,5,7,9,12,15,18,22,26,30,34,38,43,48,53,59,65,72,79,87};
static constexpr int AFLAT[95] = {
  0, 0, 0,
  0,1, 0,2, 0,3,
  0,1,4, 0,2,5, 0,3,6,
  0,1,4,7, 0,2,5,8, 0,3,6,9, 0,3,6,9, 0,3,6,9,
  0,3,6,9,12, 0,3,6,9,13, 0,3,6,9,14,
  0,3,6,9,13,16, 0,3,6,9,14,17,
  0,3,6,9,13,16,18, 0,3,6,9,14,17,19,
  0,3,6,9,13,16,18,20, 0,3,6,9,14,17,19,21};

static __device__ __forceinline__ unsigned short f2bf(float f) {
  unsigned int u = __float_as_uint(f);
  u = (u + 0x7fffu + ((u >> 16) & 1u)) >> 16;   // RTNE
  return (unsigned short)u;
}

static __device__ __forceinline__ bf16x8 pack8(float4 lo, float4 hi) {
  bf16x8 r;
  r[0] = (short)f2bf(lo.x); r[1] = (short)f2bf(lo.y);
  r[2] = (short)f2bf(lo.z); r[3] = (short)f2bf(lo.w);
  r[4] = (short)f2bf(hi.x); r[5] = (short)f2bf(hi.y);
  r[6] = (short)f2bf(hi.z); r[7] = (short)f2bf(hi.w);
  return r;
}

// ---------------------------------------------------------------------------
// K1: fused combine with 2-level K-split (z-chunks of 128 h, 4 waves x 32 h).
//   G[147][401] = [ktd_head(144x1024); deccam_w[:, :1024](3x1024)] @ [fc2_w | fc2_b]
//   H[13][267]  = [decshape_w(10x1024); deccam_w[:,1024:2048](3x1024)] @ [fc1_w | fc1_b]
// ---------------------------------------------------------------------------
__global__ __launch_bounds__(256) void combine_part(const float* __restrict__ ktd,
                                                    const float* __restrict__ dcw,
                                                    const float* __restrict__ dsw,
                                                    const float* __restrict__ w2,
                                                    const float* __restrict__ b2,
                                                    const float* __restrict__ w1,
                                                    const float* __restrict__ b1,
                                                    float* __restrict__ Gp,
                                                    float* __restrict__ Hp) {
  const bool isH = blockIdx.y >= 37;
  if (isH && blockIdx.x >= 5) return;              // H: c < 320 only (uniform exit)
  const int w = threadIdx.x >> 6, lane = threadIdx.x & 63;
  const int c = blockIdx.x * 64 + lane;
  const int h0 = blockIdx.z * 128 + w * 32;
  __shared__ float red[4][4][64];

  const float* vp[4];
  int o0;
  if (!isH) {
    o0 = blockIdx.y * 4;
    #pragma unroll
    for (int oi = 0; oi < 4; oi++) {
      int o = o0 + oi; if (o > 146) o = 146;
      vp[oi] = (o < 144) ? (ktd + (size_t)o * 1078) : (dcw + (size_t)(o - 144) * 2051);
    }
  } else {
    o0 = (blockIdx.y - 37) * 4;
    #pragma unroll
    for (int oi = 0; oi < 4; oi++) {
      int o = o0 + oi; if (o > 12) o = 12;
      vp[oi] = (o < 10) ? (dsw + (size_t)o * 1024) : (dcw + (size_t)(o - 10) * 2051 + 1024);
    }
  }

  float acc[4] = {0.f, 0.f, 0.f, 0.f};
  if (!isH) {
    #pragma unroll 16
    for (int hh = 0; hh < 32; hh++) {
      int h = h0 + hh;
      float wv = (c < 400) ? w2[h * 400 + c] : ((c == 400) ? b2[h] : 0.f);
      #pragma unroll
      for (int oi = 0; oi < 4; oi++) acc[oi] += vp[oi][h] * wv;
    }
  } else {
    #pragma unroll 16
    for (int hh = 0; hh < 32; hh++) {
      int h = h0 + hh;
      float wv = (c < 266) ? w1[h * 266 + c] : ((c == 266) ? b1[h] : 0.f);
      #pragma unroll
      for (int oi = 0; oi < 4; oi++) acc[oi] += vp[oi][h] * wv;
    }
  }

  #pragma unroll
  for (int oi = 0; oi < 4; oi++) red[w][oi][lane] = acc[oi];
  __syncthreads();
  if (w == 0) {
    #pragma unroll
    for (int oi = 0; oi < 4; oi++) {
      int o = o0 + oi;
      float s = red[0][oi][lane] + red[1][oi][lane] + red[2][oi][lane] + red[3][oi][lane];
      if (!isH) {
        if (o < 147 && c <= 400) Gp[(size_t)blockIdx.z * 59200 + o * 401 + c] = s;
      } else {
        if (o < 13 && c <= 266) Hp[(size_t)blockIdx.z * 3520 + o * 267 + c] = s;
      }
    }
  }
}

static __device__ __forceinline__ float gsum(const float* __restrict__ Gp, int t, int c) {
  float s = 0.f;
  #pragma unroll
  for (int z = 0; z < 8; z++) s += Gp[(size_t)z * 59200 + t * 401 + c];
  return s;
}
static __device__ __forceinline__ float hsum(const float* __restrict__ Hp, int t, int c) {
  float s = 0.f;
  #pragma unroll
  for (int z = 0; z < 8; z++) s += Hp[(size_t)z * 3520 + t * 267 + c];
  return s;
}

// ---------------------------------------------------------------------------
// K2: blocks 0..159: assemble fp32 M0[160][424] + bias C0[160] (8-partial sum).
//     blocks 160..162: computeS role — S[144][144] forward substitution,
//     48 columns per block, weights via wave-uniform scalar (constant-cache)
//     loads so the scalar pipe runs parallel to the VALU chain.
// ---------------------------------------------------------------------------
__global__ __launch_bounds__(256) void assemble_plus(const float* __restrict__ Gp,
                                                     const float* __restrict__ Hp,
                                                     const float* __restrict__ dcw,
                                                     const float* __restrict__ dcb,
                                                     const float* __restrict__ dsb,
                                                     const float* __restrict__ ktd,
                                                     const float* __restrict__ ktdb,
                                                     float* __restrict__ M0,
                                                     float* __restrict__ C0,
                                                     float* __restrict__ S) {
  int o = blockIdx.x;
  if (o >= 160) {                      // ---- computeS role ----
    if (threadIdx.x >= 48) return;
    int c = (o - 160) * 48 + threadIdx.x;
    float s[144];
    #pragma unroll
    for (int j = 0; j < 24; j++) {
      float v[6];
      #pragma unroll
      for (int r = 0; r < 6; r++) v[r] = (6 * j + r == c) ? 1.f : 0.f;
      #pragma unroll
      for (int a = 0; a < 8; a++) {
        if (a < ALEN[j]) {
          int anc = AFLAT[AOFF[j] + a];
          #pragma unroll
          for (int r = 0; r < 6; r++) {
            const float* w = ktd + (size_t)(6 * j + r) * 1078 + 1024 + 6 * a;
            v[r] += w[0] * s[anc * 6 + 0] + w[1] * s[anc * 6 + 1] + w[2] * s[anc * 6 + 2]
                  + w[3] * s[anc * 6 + 3] + w[4] * s[anc * 6 + 4] + w[5] * s[anc * 6 + 5];
          }
        }
      }
      #pragma unroll
      for (int r = 0; r < 6; r++) s[6 * j + r] = v[r];
    }
    #pragma unroll
    for (int t = 0; t < 144; t++) S[t * 144 + c] = s[t];
    return;
  }
  // ---- assembleM role ----
  for (int c = threadIdx.x; c < 424; c += 256) {
    float val = 0.f;
    if (c < 413) {
      if (o < 3) {
        if (c < 400) val += gsum(Gp, 144 + o, c);
        if (c < 256) val += hsum(Hp, 10 + o, c);
        if (c >= 400 && c < 410) val += hsum(Hp, 10 + o, 256 + (c - 400));
        if (c >= 410) {
          val += dcw[(size_t)o * 2051 + 2048 + (c - 410)];
          if ((c - 410) == o) val += 1.f;
        }
      } else if (o < 147) {
        int t = o - 3, j = t / 6;
        if (c < 400) val = gsum(Gp, t, c);
        int cj = c - 256 - j;            // init_pose[..., j:j+6] quirk slice
        if (cj >= 0 && cj < 6) val += ktd[(size_t)t * 1078 + 1024 + 6 * ALEN[j] + cj];
      } else if (o < 157) {
        int s = o - 147;
        if (c < 256) val = hsum(Hp, s, c);
        if (c >= 400 && c < 410) {
          val += hsum(Hp, s, 256 + (c - 400));
          if ((c - 400) == s) val += 1.f;
        }
      }
    }
    M0[o * 424 + c] = val;
  }
  if (threadIdx.x == 0 && o < 157) {
    float bv;
    if (o < 3)        bv = gsum(Gp, 144 + o, 400) + hsum(Hp, 10 + o, 266) + dcb[o];
    else if (o < 147) bv = gsum(Gp, o - 3, 400) + ktdb[o - 3];
    else              bv = hsum(Hp, o - 147, 266) + dsb[o - 147];
    C0[o] = bv;
  }
}

// ---------------------------------------------------------------------------
// K3: fold S into M: Mb[3+t][c] = bf16( sum_k S[t][k]*M0[3+k][c] + (c==256+t) )
//     2-way c-split via blockIdx.y.
// ---------------------------------------------------------------------------
__global__ __launch_bounds__(256) void foldS(const float* __restrict__ S,
                                             const float* __restrict__ M0,
                                             const float* __restrict__ C0,
                                             unsigned short* __restrict__ Mb,
                                             float* __restrict__ Cb) {
  int o = blockIdx.x;
  int c = blockIdx.y * 212 + threadIdx.x;
  bool act = (threadIdx.x < 212) && (c < 424);
  if (o < 3 || o >= 147) {
    if (act) Mb[o * 424 + c] = f2bf(M0[o * 424 + c]);
    if (threadIdx.x == 0 && blockIdx.y == 0) Cb[o] = (o < 157) ? C0[o] : 0.f;
    return;
  }
  int t = o - 3;
  __shared__ float Sl[144];
  if (threadIdx.x < 144) Sl[threadIdx.x] = S[t * 144 + threadIdx.x];
  __syncthreads();
  if (act) {
    float acc = 0.f;
    #pragma unroll 16
    for (int k = 0; k < 144; k++) acc += Sl[k] * M0[(3 + k) * 424 + c];
    if (c == 256 + t) acc += 1.f;          // + init_pose fold
    Mb[o * 424 + c] = f2bf(acc);
  }
  if (threadIdx.x == 0 && blockIdx.y == 0) {
    float acc = 0.f;
    for (int k = 0; k < 144; k++) acc += Sl[k] * C0[3 + k];
    Cb[o] = acc;
  }
}

// ---------------------------------------------------------------------------
// K4: main GEMM  out[rows x 157] = Z[rows x 424] @ Mb^T + Cb  (MFMA 16x16x32)
// No LDS, no barriers. 128-thr blocks = 2 waves x 16 rows; each wave does the
// FULL N=160 (acc[10]); all 26 fp32 A-loads staged into registers up-front so
// HBM latency is paid once, then a fully-unrolled 130-load/130-MFMA B-loop.
// ---------------------------------------------------------------------------
__global__ __launch_bounds__(128, 2) void main_gemm(const float* __restrict__ x,
                                                    const float* __restrict__ ipose,
                                                    const float* __restrict__ ishape,
                                                    const float* __restrict__ icam,
                                                    const unsigned short* __restrict__ Mb,
                                                    const float* __restrict__ Cb,
                                                    float* __restrict__ out) {
  const int w = threadIdx.x >> 6, lane = threadIdx.x & 63;
  const int m = lane & 15, g = lane >> 4;
  const int rowbase = blockIdx.x * 32 + w * 16;
  const int row = rowbase + m;
  const float* xr = x + (size_t)row * 256;
  const float* pr = ipose + (size_t)row * 144;

  // stage all A fragments (issue every load before any use)
  float4 alo[13], ahi[13];
  #pragma unroll
  for (int k = 0; k < 8; k++) {
    const float* p = xr + k * 32 + g * 8;
    alo[k] = *(const float4*)p; ahi[k] = *(const float4*)(p + 4);
  }
  #pragma unroll
  for (int k = 8; k < 12; k++) {
    const float* p = pr + (k - 8) * 32 + g * 8;
    alo[k] = *(const float4*)p; ahi[k] = *(const float4*)(p + 4);
  }
  if (g < 2) {
    const float* p = pr + 128 + g * 8;
    alo[12] = *(const float4*)p; ahi[12] = *(const float4*)(p + 4);
  } else if (g == 2) {
    const float* p = ishape + (size_t)row * 10;
    alo[12] = make_float4(p[0], p[1], p[2], p[3]);
    ahi[12] = make_float4(p[4], p[5], p[6], p[7]);
  } else {
    const float* p = ishape + (size_t)row * 10;
    const float* q = icam + (size_t)row * 3;
    alo[12] = make_float4(p[8], p[9], q[0], q[1]);
    ahi[12] = make_float4(q[2], 0.f, 0.f, 0.f);
  }
  bf16x8 areg[13];
  #pragma unroll
  for (int k = 0; k < 13; k++) areg[k] = pack8(alo[k], ahi[k]);

  f32x4 acc[10];
  #pragma unroll
  for (int n = 0; n < 10; n++) acc[n] = (f32x4){0.f, 0.f, 0.f, 0.f};

  #pragma unroll
  for (int k = 0; k < 13; k++) {
    #pragma unroll
    for (int n = 0; n < 10; n++) {
      bf16x8 b = *(const bf16x8*)&Mb[(size_t)(n * 16 + m) * 424 + k * 32 + g * 8];
      acc[n] = __builtin_amdgcn_mfma_f32_16x16x32_bf16(areg[k], b, acc[n], 0, 0, 0);
    }
  }

  // epilogue: C/D layout col=lane&15, row=(lane>>4)*4+reg  [m89-verified]
  #pragma unroll
  for (int n = 0; n < 10; n++) {
    int col = n * 16 + m;
    if (col < 157) {
      float bias = Cb[col];
      #pragma unroll
      for (int q = 0; q < 4; q++)
        out[(size_t)(rowbase + g * 4 + q) * 157 + col] = acc[n][q] + bias;
    }
  }
}

// ---------------------------------------------------------------------------
extern "C" void kernel_launch(void* const* d_in, const int* in_sizes, int n_in,
                              void* d_out, int out_size, void* d_ws, size_t ws_size,
                              hipStream_t stream) {
  const float* x      = (const float*)d_in[0];
  const float* ipose  = (const float*)d_in[1];
  const float* ishape = (const float*)d_in[2];
  const float* icam   = (const float*)d_in[3];
  const float* fc1w   = (const float*)d_in[4];
  const float* fc1b   = (const float*)d_in[5];
  const float* fc2w   = (const float*)d_in[6];
  const float* fc2b   = (const float*)d_in[7];
  const float* dsw    = (const float*)d_in[8];
  const float* dsb    = (const float*)d_in[9];
  const float* dcw    = (const float*)d_in[10];
  const float* dcb    = (const float*)d_in[11];
  const float* ktd    = (const float*)d_in[12];
  const float* ktdb   = (const float*)d_in[13];
  int rows = in_sizes[0] / 256;
  float* ws = (float*)d_ws;

  float* Gp = ws;                                      // 8*59200 = 473600 f
  float* Hp = ws + 473600;                             // 8*3520  = 28160 f -> 501760
  float* M0 = ws + 501760;                             // 160*424 = 67840 f -> 569600
  float* C0 = ws + 569600;                             // 160 f -> 569760
  float* S  = ws + 569760;                             // 144*144 = 20736 f -> 590496
  float* Cb = ws + 590496;                             // 160 f -> 590656
  unsigned short* Mb = (unsigned short*)(ws + 590656); // byte 2362624 (16-aligned)

  combine_part<<<dim3(7, 41, 8), 256, 0, stream>>>(ktd, dcw, dsw, fc2w, fc2b,
                                                   fc1w, fc1b, Gp, Hp);
  assemble_plus<<<163, 256, 0, stream>>>(Gp, Hp, dcw, dcb, dsb, ktd, ktdb,
                                         M0, C0, S);
  foldS<<<dim3(160, 2), 256, 0, stream>>>(S, M0, C0, Mb, Cb);
  main_gemm<<<rows / 32, 128, 0, stream>>>(x, ipose, ishape, icam, Mb, Cb,
                                           (float*)d_out);
}

// Round 6
// 57.880 us; speedup vs baseline: 2.2609x; 1.7304x over previous
//
#include <hip/hip_runtime.h>
#include <hip/hip_bf16.h>

typedef __attribute__((ext_vector_type(8))) short bf16x8;
typedef __attribute__((ext_vector_type(4))) float f32x4;

// Kinematic tree ancestor tables (full ancestor paths, from reference)
static constexpr int ALEN[24] = {0,1,1,1,2,2,2,3,3,3,4,4,4,4,4,5,5,5,6,6,7,7,8,8};
static constexpr int AOFF[24] = {0,0,1,2,3,5,7,9,12,15,18,22,26,30,34,38,43,48,53,59,65,72,79,87};
static constexpr int AFLAT[95] = {
  0, 0, 0,
  0,1, 0,2, 0,3,
  0,1,4, 0,2,5, 0,3,6,
  0,1,4,7, 0,2,5,8, 0,3,6,9, 0,3,6,9, 0,3,6,9,
  0,3,6,9,12, 0,3,6,9,13, 0,3,6,9,14,
  0,3,6,9,13,16, 0,3,6,9,14,17,
  0,3,6,9,13,16,18, 0,3,6,9,14,17,19,
  0,3,6,9,13,16,18,20, 0,3,6,9,14,17,19,21};
// Joints grouped by tree depth (ALEN value); independent within a level.
static constexpr int LVLN[9] = {1,3,3,3,5,3,2,2,2};
static constexpr int LVLJ[9][5] = {
  {0,0,0,0,0},{1,2,3,0,0},{4,5,6,0,0},{7,8,9,0,0},{10,11,12,13,14},
  {15,16,17,0,0},{18,19,0,0,0},{20,21,0,0,0},{22,23,0,0,0}};

static __device__ __forceinline__ unsigned short f2bf(float f) {
  unsigned int u = __float_as_uint(f);
  u = (u + 0x7fffu + ((u >> 16) & 1u)) >> 16;   // RTNE
  return (unsigned short)u;
}

static __device__ __forceinline__ bf16x8 pack8(float4 lo, float4 hi) {
  bf16x8 r;
  r[0] = (short)f2bf(lo.x); r[1] = (short)f2bf(lo.y);
  r[2] = (short)f2bf(lo.z); r[3] = (short)f2bf(lo.w);
  r[4] = (short)f2bf(hi.x); r[5] = (short)f2bf(hi.y);
  r[6] = (short)f2bf(hi.z); r[7] = (short)f2bf(hi.w);
  return r;
}

// ---------------------------------------------------------------------------
// K1: fused combine (y<41) + computeS (y==41).
//   G[147][401] = [ktd_head; deccam_w[:, :1024]] @ [fc2_w | fc2_b]
//   H[13][267]  = [decshape_w; deccam_w[:,1024:2048]] @ [fc1_w | fc1_b]
//   S[144][144]: pose = S @ base — level-synchronous forward substitution,
//   36 columns per block (4 blocks), S slice in LDS, no per-thread arrays.
// ---------------------------------------------------------------------------
__global__ __launch_bounds__(256) void combine_plus(const float* __restrict__ ktd,
                                                    const float* __restrict__ dcw,
                                                    const float* __restrict__ dsw,
                                                    const float* __restrict__ w2,
                                                    const float* __restrict__ b2,
                                                    const float* __restrict__ w1,
                                                    const float* __restrict__ b1,
                                                    float* __restrict__ Gp,
                                                    float* __restrict__ Hp,
                                                    float* __restrict__ S) {
  __shared__ float shpool[5760];                 // 23 KB: Sl[144][40] / red[4][4][64]
  const int tid = threadIdx.x;

  if (blockIdx.y == 41) {                        // ---- computeS role ----
    if (blockIdx.x >= 4 || blockIdx.z != 0) return;
    float* Sl = shpool;                          // [144][40]
    const int c0 = blockIdx.x * 36;
    for (int lv = 0; lv < 9; lv++) {
      int units = LVLN[lv] * 54;                 // joints * 6 rows * 9 colquads
      for (int u = tid; u < units; u += 256) {
        int jj = u / 54, rem = u % 54, r = rem / 9, q = rem % 9;
        int j = LVLJ[lv][jj];
        int t = 6 * j + r;
        int cb = c0 + q * 4;
        f32x4 v;
        v[0] = (t == cb)     ? 1.f : 0.f;
        v[1] = (t == cb + 1) ? 1.f : 0.f;
        v[2] = (t == cb + 2) ? 1.f : 0.f;
        v[3] = (t == cb + 3) ? 1.f : 0.f;
        const float* wrow = ktd + (size_t)t * 1078 + 1024;
        for (int a = 0; a < ALEN[j]; a++) {
          int anc = AFLAT[AOFF[j] + a];
          const float* w = wrow + 6 * a;
          #pragma unroll
          for (int k = 0; k < 6; k++) {
            f32x4 s4 = *(const f32x4*)&Sl[(anc * 6 + k) * 40 + q * 4];
            float wk = w[k];
            v[0] += wk * s4[0]; v[1] += wk * s4[1];
            v[2] += wk * s4[2]; v[3] += wk * s4[3];
          }
        }
        *(f32x4*)&Sl[t * 40 + q * 4] = v;        // current-level rows: no readers yet
      }
      __syncthreads();
    }
    for (int i = tid; i < 144 * 36; i += 256) {
      int t = i / 36, cc = i % 36;
      S[t * 144 + c0 + cc] = Sl[t * 40 + cc];
    }
    return;
  }

  // ---- combine role ----
  const bool isH = blockIdx.y >= 37;
  if (isH && blockIdx.x >= 5) return;            // H: c < 320 only (uniform exit)
  float (*red)[4][64] = (float(*)[4][64])shpool; // [4][4][64]
  const int w = tid >> 6, lane = tid & 63;
  const int c = blockIdx.x * 64 + lane;
  const int h0 = blockIdx.z * 128 + w * 32;

  const float* vp[4];
  int o0;
  if (!isH) {
    o0 = blockIdx.y * 4;
    #pragma unroll
    for (int oi = 0; oi < 4; oi++) {
      int o = o0 + oi; if (o > 146) o = 146;
      vp[oi] = (o < 144) ? (ktd + (size_t)o * 1078) : (dcw + (size_t)(o - 144) * 2051);
    }
  } else {
    o0 = (blockIdx.y - 37) * 4;
    #pragma unroll
    for (int oi = 0; oi < 4; oi++) {
      int o = o0 + oi; if (o > 12) o = 12;
      vp[oi] = (o < 10) ? (dsw + (size_t)o * 1024) : (dcw + (size_t)(o - 10) * 2051 + 1024);
    }
  }

  float acc[4] = {0.f, 0.f, 0.f, 0.f};
  if (!isH) {
    #pragma unroll 16
    for (int hh = 0; hh < 32; hh++) {
      int h = h0 + hh;
      float wv = (c < 400) ? w2[h * 400 + c] : ((c == 400) ? b2[h] : 0.f);
      #pragma unroll
      for (int oi = 0; oi < 4; oi++) acc[oi] += vp[oi][h] * wv;
    }
  } else {
    #pragma unroll 16
    for (int hh = 0; hh < 32; hh++) {
      int h = h0 + hh;
      float wv = (c < 266) ? w1[h * 266 + c] : ((c == 266) ? b1[h] : 0.f);
      #pragma unroll
      for (int oi = 0; oi < 4; oi++) acc[oi] += vp[oi][h] * wv;
    }
  }

  #pragma unroll
  for (int oi = 0; oi < 4; oi++) red[w][oi][lane] = acc[oi];
  __syncthreads();
  if (w == 0) {
    #pragma unroll
    for (int oi = 0; oi < 4; oi++) {
      int o = o0 + oi;
      float s = red[0][oi][lane] + red[1][oi][lane] + red[2][oi][lane] + red[3][oi][lane];
      if (!isH) {
        if (o < 147 && c <= 400) Gp[(size_t)blockIdx.z * 59200 + o * 401 + c] = s;
      } else {
        if (o < 13 && c <= 266) Hp[(size_t)blockIdx.z * 3520 + o * 267 + c] = s;
      }
    }
  }
}

static __device__ __forceinline__ float gsum(const float* __restrict__ Gp, int t, int c) {
  float s = 0.f;
  #pragma unroll
  for (int z = 0; z < 8; z++) s += Gp[(size_t)z * 59200 + t * 401 + c];
  return s;
}
static __device__ __forceinline__ float hsum(const float* __restrict__ Hp, int t, int c) {
  float s = 0.f;
  #pragma unroll
  for (int z = 0; z < 8; z++) s += Hp[(size_t)z * 3520 + t * 267 + c];
  return s;
}

// ---------------------------------------------------------------------------
// K2: assemble fp32 M0[160][424] + bias C0[160], summing 8 K-chunk partials.
// z layout: [0:256)=x  [256:400)=init_pose  [400:410)=init_shape  [410:413)=init_cam
// out rows: [0:3)=cam  [3:147)=pose BASE  [147:157)=shape
// ---------------------------------------------------------------------------
__global__ __launch_bounds__(256) void assembleM(const float* __restrict__ Gp,
                                                 const float* __restrict__ Hp,
                                                 const float* __restrict__ dcw,
                                                 const float* __restrict__ dcb,
                                                 const float* __restrict__ dsb,
                                                 const float* __restrict__ ktd,
                                                 const float* __restrict__ ktdb,
                                                 float* __restrict__ M0,
                                                 float* __restrict__ C0) {
  int o = blockIdx.x;
  for (int c = threadIdx.x; c < 424; c += 256) {
    float val = 0.f;
    if (c < 413) {
      if (o < 3) {
        if (c < 400) val += gsum(Gp, 144 + o, c);
        if (c < 256) val += hsum(Hp, 10 + o, c);
        if (c >= 400 && c < 410) val += hsum(Hp, 10 + o, 256 + (c - 400));
        if (c >= 410) {
          val += dcw[(size_t)o * 2051 + 2048 + (c - 410)];
          if ((c - 410) == o) val += 1.f;
        }
      } else if (o < 147) {
        int t = o - 3, j = t / 6;
        if (c < 400) val = gsum(Gp, t, c);
        int cj = c - 256 - j;            // init_pose[..., j:j+6] quirk slice
        if (cj >= 0 && cj < 6) val += ktd[(size_t)t * 1078 + 1024 + 6 * ALEN[j] + cj];
      } else if (o < 157) {
        int s = o - 147;
        if (c < 256) val = hsum(Hp, s, c);
        if (c >= 400 && c < 410) {
          val += hsum(Hp, s, 256 + (c - 400));
          if ((c - 400) == s) val += 1.f;
        }
      }
    }
    M0[o * 424 + c] = val;
  }
  if (threadIdx.x == 0 && o < 157) {
    float bv;
    if (o < 3)        bv = gsum(Gp, 144 + o, 400) + hsum(Hp, 10 + o, 266) + dcb[o];
    else if (o < 147) bv = gsum(Gp, o - 3, 400) + ktdb[o - 3];
    else              bv = hsum(Hp, o - 147, 266) + dsb[o - 147];
    C0[o] = bv;
  }
}

// ---------------------------------------------------------------------------
// K3: fold S into M: Mb[3+t][c] = bf16( sum_k S[t][k]*M0[3+k][c] + (c==256+t) )
//     2-way c-split via blockIdx.y.
// ---------------------------------------------------------------------------
__global__ __launch_bounds__(256) void foldS(const float* __restrict__ S,
                                             const float* __restrict__ M0,
                                             const float* __restrict__ C0,
                                             unsigned short* __restrict__ Mb,
                                             float* __restrict__ Cb) {
  int o = blockIdx.x;
  int c = blockIdx.y * 212 + threadIdx.x;
  bool act = (threadIdx.x < 212) && (c < 424);
  if (o < 3 || o >= 147) {
    if (act) Mb[o * 424 + c] = f2bf(M0[o * 424 + c]);
    if (threadIdx.x == 0 && blockIdx.y == 0) Cb[o] = (o < 157) ? C0[o] : 0.f;
    return;
  }
  int t = o - 3;
  __shared__ float Sl[144];
  if (threadIdx.x < 144) Sl[threadIdx.x] = S[t * 144 + threadIdx.x];
  __syncthreads();
  if (act) {
    float acc = 0.f;
    #pragma unroll 16
    for (int k = 0; k < 144; k++) acc += Sl[k] * M0[(3 + k) * 424 + c];
    if (c == 256 + t) acc += 1.f;          // + init_pose fold
    Mb[o * 424 + c] = f2bf(acc);
  }
  if (threadIdx.x == 0 && blockIdx.y == 0) {
    float acc = 0.f;
    for (int k = 0; k < 144; k++) acc += Sl[k] * C0[3 + k];
    Cb[o] = acc;
  }
}

// ---------------------------------------------------------------------------
// K4: main GEMM  out[rows x 157] = Z[rows x 424] @ Mb^T + Cb  (MFMA 16x16x32)
// 512 threads = 8 waves x 16 rows (128 rows/block), FULL N=160 per wave.
// Whole Mb (160x424 bf16 = 132.5 KB) staged into LDS once per block -> B-reads
// come from LDS (no L2 hot-spot); inputs read exactly once (no N-split).
// ---------------------------------------------------------------------------
__global__ __launch_bounds__(512, 2) void main_gemm(const float* __restrict__ x,
                                                    const float* __restrict__ ipose,
                                                    const float* __restrict__ ishape,
                                                    const float* __restrict__ icam,
                                                    const unsigned short* __restrict__ Mb,
                                                    const float* __restrict__ Cb,
                                                    float* __restrict__ out) {
  __shared__ unsigned short Bl[160 * 424];       // 132.5 KB
  const int tid = threadIdx.x;

  {
    const bf16x8* src = (const bf16x8*)Mb;
    bf16x8* dst = (bf16x8*)Bl;
    for (int i = tid; i < 160 * 424 / 8; i += 512) dst[i] = src[i];
  }
  __syncthreads();

  const int w = tid >> 6, lane = tid & 63;
  const int m = lane & 15, g = lane >> 4;
  const int rowbase = blockIdx.x * 128 + w * 16;
  const int row = rowbase + m;
  const float* xr = x + (size_t)row * 256;
  const float* pr = ipose + (size_t)row * 144;

  // stage all A fragments (issue every load before any use)
  float4 alo[13], ahi[13];
  #pragma unroll
  for (int k = 0; k < 8; k++) {
    const float* p = xr + k * 32 + g * 8;
    alo[k] = *(const float4*)p; ahi[k] = *(const float4*)(p + 4);
  }
  #pragma unroll
  for (int k = 8; k < 12; k++) {
    const float* p = pr + (k - 8) * 32 + g * 8;
    alo[k] = *(const float4*)p; ahi[k] = *(const float4*)(p + 4);
  }
  if (g < 2) {
    const float* p = pr + 128 + g * 8;
    alo[12] = *(const float4*)p; ahi[12] = *(const float4*)(p + 4);
  } else if (g == 2) {
    const float* p = ishape + (size_t)row * 10;
    alo[12] = make_float4(p[0], p[1], p[2], p[3]);
    ahi[12] = make_float4(p[4], p[5], p[6], p[7]);
  } else {
    const float* p = ishape + (size_t)row * 10;
    const float* q = icam + (size_t)row * 3;
    alo[12] = make_float4(p[8], p[9], q[0], q[1]);
    ahi[12] = make_float4(q[2], 0.f, 0.f, 0.f);
  }
  bf16x8 areg[13];
  #pragma unroll
  for (int k = 0; k < 13; k++) areg[k] = pack8(alo[k], ahi[k]);

  f32x4 acc[10];
  #pragma unroll
  for (int n = 0; n < 10; n++) acc[n] = (f32x4){0.f, 0.f, 0.f, 0.f};

  #pragma unroll
  for (int k = 0; k < 13; k++) {
    #pragma unroll
    for (int n = 0; n < 10; n++) {
      bf16x8 b = *(const bf16x8*)&Bl[(n * 16 + m) * 424 + k * 32 + g * 8];
      acc[n] = __builtin_amdgcn_mfma_f32_16x16x32_bf16(areg[k], b, acc[n], 0, 0, 0);
    }
  }

  // epilogue: C/D layout col=lane&15, row=(lane>>4)*4+reg  [m89-verified]
  #pragma unroll
  for (int n = 0; n < 10; n++) {
    int col = n * 16 + m;
    if (col < 157) {
      float bias = Cb[col];
      #pragma unroll
      for (int q = 0; q < 4; q++)
        out[(size_t)(rowbase + g * 4 + q) * 157 + col] = acc[n][q] + bias;
    }
  }
}

// ---------------------------------------------------------------------------
extern "C" void kernel_launch(void* const* d_in, const int* in_sizes, int n_in,
                              void* d_out, int out_size, void* d_ws, size_t ws_size,
                              hipStream_t stream) {
  const float* x      = (const float*)d_in[0];
  const float* ipose  = (const float*)d_in[1];
  const float* ishape = (const float*)d_in[2];
  const float* icam   = (const float*)d_in[3];
  const float* fc1w   = (const float*)d_in[4];
  const float* fc1b   = (const float*)d_in[5];
  const float* fc2w   = (const float*)d_in[6];
  const float* fc2b   = (const float*)d_in[7];
  const float* dsw    = (const float*)d_in[8];
  const float* dsb    = (const float*)d_in[9];
  const float* dcw    = (const float*)d_in[10];
  const float* dcb    = (const float*)d_in[11];
  const float* ktd    = (const float*)d_in[12];
  const float* ktdb   = (const float*)d_in[13];
  int rows = in_sizes[0] / 256;
  float* ws = (float*)d_ws;

  float* Gp = ws;                                      // 8*59200 = 473600 f
  float* Hp = ws + 473600;                             // 8*3520  = 28160 f -> 501760
  float* M0 = ws + 501760;                             // 160*424 = 67840 f -> 569600
  float* C0 = ws + 569600;                             // 160 f -> 569760
  float* S  = ws + 569760;                             // 144*144 = 20736 f -> 590496
  float* Cb = ws + 590496;                             // 160 f -> 590656
  unsigned short* Mb = (unsigned short*)(ws + 590656); // byte 2362624 (16-aligned)

  combine_plus<<<dim3(7, 42, 8), 256, 0, stream>>>(ktd, dcw, dsw, fc2w, fc2b,
                                                   fc1w, fc1b, Gp, Hp, S);
  assembleM<<<160, 256, 0, stream>>>(Gp, Hp, dcw, dcb, dsb, ktd, ktdb, M0, C0);
  foldS<<<dim3(160, 2), 256, 0, stream>>>(S, M0, C0, Mb, Cb);
  main_gemm<<<rows / 128, 512, 0, stream>>>(x, ipose, ishape, icam, Mb, Cb,
                                            (float*)d_out);
}